// Round 3
// baseline (228.552 us; speedup 1.0000x reference)
//
#include <hip/hip_runtime.h>
#include <math.h>

#define SRC_H 480
#define SRC_W 640
#define RES_H 384
#define RES_W 512
#define NT 16
#define NPIX (RES_H * RES_W)        /* 196608 */
#define PLANE (SRC_H * SRC_W)       /* 307200 */
#define NCH 30                      /* chunks per plane in feat pass */
#define SCALE_X (639.0f / 511.0f)
#define SCALE_Y (479.0f / 383.0f)

typedef float f32x4 __attribute__((ext_vector_type(4)));
typedef float f32x2 __attribute__((ext_vector_type(2)));

/* output layout (floats, concatenated in return order) */
#define O_SPARSE 0
#define N_SPARSE (NT * 96 * 128 * 2)            /* 393216 */
#define O_XY (O_SPARSE + N_SPARSE)
#define N_XY (NT * NPIX * 2)
#define O_Z (O_XY + N_XY)
#define N_Z (NT * NPIX)
#define O_VIS (O_Z + N_Z)
#define O_TRAJ (O_VIS + N_Z)

/* ws layout: double part[48*30] (11520 B) -> float ofs 2880; disp[32] @2880; fm[16] @2912 */

__global__ __launch_bounds__(256) void feat_kernel(
        const float* __restrict__ video, double* __restrict__ part) {
    int b = blockIdx.x;     /* 0..29 : 16 source rows each */
    int plane = blockIdx.y; /* 0..47 : t*3+c */
    int tid = threadIdx.x;
    __shared__ float axs[640];
    __shared__ float ays[16];

    for (int j = tid; j < 656; j += 256) {
        if (j < 16) {
            int i = b * 16 + j; /* source row */
            const float s = 479.0f / 383.0f;
            float acc = 0.f;
            int lo = (int)floorf((float)(i - 1) / s) - 2; if (lo < 0) lo = 0;
            int hi = (int)ceilf((float)(i + 1) / s) + 2; if (hi > RES_H - 1) hi = RES_H - 1;
            for (int oy = lo; oy <= hi; ++oy) {
                float ys = (float)oy * s;
                int y0 = (int)floorf(ys);
                float wy = ys - (float)y0;
                int y1 = min(y0 + 1, SRC_H - 1);
                if (y0 == i) acc += (1.f - wy);
                if (y1 == i) acc += wy;
            }
            ays[j] = acc * (1.0f / RES_H);
        } else {
            int xs = j - 16;
            const float s2 = 639.0f / 511.0f;
            float acc = 0.f;
            int lo = (int)floorf((float)(xs - 1) / s2) - 2; if (lo < 0) lo = 0;
            int hi = (int)ceilf((float)(xs + 1) / s2) + 2; if (hi > RES_W - 1) hi = RES_W - 1;
            for (int ox = lo; ox <= hi; ++ox) {
                float xv = (float)ox * s2;
                int x0 = (int)floorf(xv);
                float wx = xv - (float)x0;
                int x1 = min(x0 + 1, SRC_W - 1);
                if (x0 == xs) acc += (1.f - wx);
                if (x1 == xs) acc += wx;
            }
            axs[xs] = acc * (1.0f / RES_W);
        }
    }
    __syncthreads();

    const f32x4* v = (const f32x4*)(video + (size_t)plane * PLANE + (size_t)b * 10240);
    double s = 0.0;
#pragma unroll
    for (int it = 0; it < 10; ++it) {
        int idx = it * 256 + tid;          /* 0..2559 float4s = 16 rows */
        f32x4 q = v[idx];
        int row = idx / 160;               /* 160 float4 per row */
        int xq = (idx - row * 160) * 4;
        float w = ays[row];
        s += (double)(w * axs[xq + 0]) * (double)q.x
           + (double)(w * axs[xq + 1]) * (double)q.y
           + (double)(w * axs[xq + 2]) * (double)q.z
           + (double)(w * axs[xq + 3]) * (double)q.w;
    }

    __shared__ double sh[256];
    sh[tid] = s;
    __syncthreads();
    for (int off = 128; off > 0; off >>= 1) {
        if (tid < off) sh[tid] += sh[tid + off];
        __syncthreads();
    }
    if (tid == 0) part[plane * NCH + b] = sh[0];
}

__global__ void finalize_kernel(const double* __restrict__ part,
                                float* __restrict__ disp, float* __restrict__ fm) {
    __shared__ float feats[48];
    int tid = threadIdx.x;
    if (tid < 48) {
        double s = 0.0;
        for (int k = 0; k < NCH; ++k) s += part[tid * NCH + k];
        feats[tid] = (float)s;
    }
    __syncthreads();
    if (tid < NT) {
        float f0 = feats[tid * 3 + 0];
        float f1 = feats[tid * 3 + 1];
        float f2 = feats[tid * 3 + 2];
        disp[2 * tid + 0] = tanhf(f0) * 2.0f;
        disp[2 * tid + 1] = tanhf(f1) * 2.0f;
        fm[tid] = ((f0 + f1) + f2) / 3.0f;
    }
}

__global__ __launch_bounds__(256) void main_kernel(
        const float* __restrict__ video, const float* __restrict__ depth,
        const float* __restrict__ disp, const float* __restrict__ fm,
        float* __restrict__ out) {
    int gid = blockIdx.x * 256 + threadIdx.x;   /* one thread = 4 pixels */
    int t = gid / (NPIX / 4);
    int rem4 = gid - t * (NPIX / 4);
    int y = rem4 >> 7;
    int x0 = (rem4 & 127) << 2;

    float dx = disp[2 * t + 0];
    float dy = disp[2 * t + 1];
    float fmt = fm[t];
    float tf = (float)t;

    /* y/t-invariant depth-row setup (valid for covered pixels) */
    float tyv = fminf(fmaxf((float)y + tf * dy, 0.f), 383.f);
    int y0 = (int)floorf(tyv);
    int y1 = min(y0 + 1, RES_H - 1);
    float wy = tyv - (float)y0;
    const float* dep = depth + (size_t)t * PLANE;
    int dro0 = (y0 + (y0 >> 2)) * SRC_W;
    int dro1 = (y1 + (y1 >> 2)) * SRC_W;
    float ytrk_c = tyv * SCALE_Y;

    const float* vt = video + (size_t)t * 3 * PLANE;

    float xt[4], yt[4], dv[4], vv[4], X4[4], Y4[4], col0[4], col1[4], col2[4];

#pragma unroll
    for (int k = 0; k < 4; ++k) {
        int x = x0 + k;
        bool covered = (x < 510);
        float xtrk = 0.f, ytrk = 0.f, dval = 0.f, visv = 0.f;
        if (covered) {
            float txv = fminf(fmaxf((float)x + tf * dx, 0.f), 511.f);
            int xi0 = (int)floorf(txv);
            int xi1 = min(xi0 + 1, RES_W - 1);
            float wx = txv - (float)xi0;
            int sx0 = xi0 + (xi0 >> 2);
            int sx1 = xi1 + (xi1 >> 2);
            float d00 = dep[dro0 + sx0];
            float d01 = dep[dro0 + sx1];
            float d10 = dep[dro1 + sx0];
            float d11 = dep[dro1 + sx1];
            dval = d00 * ((1.f - wx) * (1.f - wy)) + d01 * (wx * (1.f - wy))
                 + d10 * ((1.f - wx) * wy) + d11 * (wx * wy);
            float z = 3.0f * __sinf(0.05f * (float)(x + y)) + fmt;
            visv = (z > 1.38629436f) ? 1.f : 0.f;   /* sigmoid(z)>0.8 <=> z>ln4 */
            xtrk = txv * SCALE_X;
            ytrk = ytrk_c;
        }
        xt[k] = xtrk; yt[k] = ytrk; dv[k] = dval; vv[k] = visv;
        X4[k] = (xtrk - 320.f) / 640.f;
        Y4[k] = (ytrk - 240.f) / 640.f;

        /* grid-sample coords, stepwise like the reference */
        float a1 = xtrk / 640.f; float b1 = 2.f * (a1 - 0.5f); float c1 = b1 + 1.f;
        float px = (c1 * 0.5f) * 639.f;
        float a2 = ytrk / 480.f; float b2 = 2.f * (a2 - 0.5f); float c2 = b2 + 1.f;
        float py = (c2 * 0.5f) * 479.f;
        px = fminf(fmaxf(px, 0.f), 639.f);
        py = fminf(fmaxf(py, 0.f), 479.f);
        int cx0 = (int)floorf(px); int cx1 = min(cx0 + 1, SRC_W - 1); float cwx = px - (float)cx0;
        int cy0 = (int)floorf(py); int cy1 = min(cy0 + 1, SRC_H - 1); float cwy = py - (float)cy0;
        float w00 = (1.f - cwx) * (1.f - cwy), w01 = cwx * (1.f - cwy);
        float w10 = (1.f - cwx) * cwy,         w11 = cwx * cwy;
        int r0 = cy0 * SRC_W, r1 = cy1 * SRC_W;
        {
            const float* vc = vt;
            col0[k] = vc[r0 + cx0] * w00 + vc[r0 + cx1] * w01 + vc[r1 + cx0] * w10 + vc[r1 + cx1] * w11;
            vc += PLANE;
            col1[k] = vc[r0 + cx0] * w00 + vc[r0 + cx1] * w01 + vc[r1 + cx0] * w10 + vc[r1 + cx1] * w11;
            vc += PLANE;
            col2[k] = vc[r0 + cx0] * w00 + vc[r0 + cx1] * w01 + vc[r1 + cx0] * w10 + vc[r1 + cx1] * w11;
        }
    }

    size_t tb0 = (size_t)t * NPIX + ((size_t)y << 9) + (size_t)x0;

    f32x4* oxy = (f32x4*)(out + O_XY + tb0 * 2);
    __builtin_nontemporal_store((f32x4){xt[0], yt[0], xt[1], yt[1]}, oxy);
    __builtin_nontemporal_store((f32x4){xt[2], yt[2], xt[3], yt[3]}, oxy + 1);
    __builtin_nontemporal_store((f32x4){dv[0], dv[1], dv[2], dv[3]},
                                (f32x4*)(out + O_Z + tb0));
    __builtin_nontemporal_store((f32x4){vv[0], vv[1], vv[2], vv[3]},
                                (f32x4*)(out + O_VIS + tb0));

    /* traj: 28 floats = 7 float4; element e -> pixel e/7, comp e%7 */
    float* trp = out + O_TRAJ + tb0 * 7;
#define TRC(k, c) ((c) == 0 ? X4[k] : (c) == 1 ? Y4[k] : (c) == 2 ? dv[k] : \
                   (c) == 3 ? col0[k] : (c) == 4 ? col1[k] : (c) == 5 ? col2[k] : vv[k])
#pragma unroll
    for (int q = 0; q < 7; ++q) {
        int e = q * 4;
        f32x4 w = {TRC((e + 0) / 7, (e + 0) % 7),
                   TRC((e + 1) / 7, (e + 1) % 7),
                   TRC((e + 2) / 7, (e + 2) % 7),
                   TRC((e + 3) / 7, (e + 3) % 7)};
        __builtin_nontemporal_store(w, (f32x4*)(trp + e));
    }
#undef TRC

    if ((y & 3) == 0) {
        int ns = (y >> 2) * 128 + (x0 >> 2);
        size_t sb = (size_t)t * (96 * 128) + (size_t)ns;
        f32x2* sp = (f32x2*)(out + O_SPARSE + sb * 2);
        __builtin_nontemporal_store((f32x2){xt[0], yt[0]}, sp);
    }
}

extern "C" void kernel_launch(void* const* d_in, const int* in_sizes, int n_in,
                              void* d_out, int out_size, void* d_ws, size_t ws_size,
                              hipStream_t stream) {
    const float* video = (const float*)d_in[0];
    const float* depth = (const float*)d_in[1];
    float* out = (float*)d_out;

    double* part = (double*)d_ws;            /* 48*30 doubles = 11520 B */
    float* wsf = (float*)d_ws;
    float* disp = wsf + 2880;                /* 32 */
    float* fm = wsf + 2912;                  /* 16 */

    feat_kernel<<<dim3(NCH, NT * 3), 256, 0, stream>>>(video, part);
    finalize_kernel<<<1, 64, 0, stream>>>(part, disp, fm);
    main_kernel<<<(NT * NPIX / 4) / 256, 256, 0, stream>>>(video, depth, disp, fm, out);
}

// Round 4
// 57.492 us; speedup vs baseline: 3.9754x; 3.9754x over previous
//
#include <hip/hip_runtime.h>
#include <math.h>

#define SRC_H 480
#define SRC_W 640
#define RES_H 384
#define RES_W 512
#define NT 16
#define NPIX (RES_H * RES_W)        /* 196608 */
#define PLANE (SRC_H * SRC_W)       /* 307200 */
#define NCH 30                      /* chunks per plane in feat pass */
#define SCALE_X (639.0f / 511.0f)
#define SCALE_Y (479.0f / 383.0f)

typedef float f32x4 __attribute__((ext_vector_type(4)));
typedef float f32x2 __attribute__((ext_vector_type(2)));

/* output layout (floats, concatenated in return order) */
#define O_SPARSE 0
#define N_SPARSE (NT * 96 * 128 * 2)            /* 393216 */
#define O_XY (O_SPARSE + N_SPARSE)
#define N_XY (NT * NPIX * 2)
#define O_Z (O_XY + N_XY)
#define N_Z (NT * NPIX)
#define O_VIS (O_Z + N_Z)
#define O_TRAJ (O_VIS + N_Z)

/* ws layout: double part[48*30] (11520 B) -> float ofs 2880; disp[32] @2880; fm[16] @2912 */

__global__ __launch_bounds__(256) void feat_kernel(
        const float* __restrict__ video, double* __restrict__ part) {
    int b = blockIdx.x;     /* 0..29 : 16 source rows each */
    int plane = blockIdx.y; /* 0..47 : t*3+c */
    int tid = threadIdx.x;
    __shared__ float axs[640];
    __shared__ float ays[16];

    for (int j = tid; j < 656; j += 256) {
        if (j < 16) {
            int i = b * 16 + j; /* source row */
            const float s = 479.0f / 383.0f;
            float acc = 0.f;
            int lo = (int)floorf((float)(i - 1) / s) - 2; if (lo < 0) lo = 0;
            int hi = (int)ceilf((float)(i + 1) / s) + 2; if (hi > RES_H - 1) hi = RES_H - 1;
            for (int oy = lo; oy <= hi; ++oy) {
                float ys = (float)oy * s;
                int y0 = (int)floorf(ys);
                float wy = ys - (float)y0;
                int y1 = min(y0 + 1, SRC_H - 1);
                if (y0 == i) acc += (1.f - wy);
                if (y1 == i) acc += wy;
            }
            ays[j] = acc * (1.0f / RES_H);
        } else {
            int xs = j - 16;
            const float s2 = 639.0f / 511.0f;
            float acc = 0.f;
            int lo = (int)floorf((float)(xs - 1) / s2) - 2; if (lo < 0) lo = 0;
            int hi = (int)ceilf((float)(xs + 1) / s2) + 2; if (hi > RES_W - 1) hi = RES_W - 1;
            for (int ox = lo; ox <= hi; ++ox) {
                float xv = (float)ox * s2;
                int x0 = (int)floorf(xv);
                float wx = xv - (float)x0;
                int x1 = min(x0 + 1, SRC_W - 1);
                if (x0 == xs) acc += (1.f - wx);
                if (x1 == xs) acc += wx;
            }
            axs[xs] = acc * (1.0f / RES_W);
        }
    }
    __syncthreads();

    const f32x4* v = (const f32x4*)(video + (size_t)plane * PLANE + (size_t)b * 10240);
    double s = 0.0;
#pragma unroll
    for (int it = 0; it < 10; ++it) {
        int idx = it * 256 + tid;          /* 0..2559 float4s = 16 rows */
        f32x4 q = v[idx];
        int row = idx / 160;               /* 160 float4 per row */
        int xq = (idx - row * 160) * 4;
        float w = ays[row];
        s += (double)(w * axs[xq + 0]) * (double)q.x
           + (double)(w * axs[xq + 1]) * (double)q.y
           + (double)(w * axs[xq + 2]) * (double)q.z
           + (double)(w * axs[xq + 3]) * (double)q.w;
    }

    __shared__ double sh[256];
    sh[tid] = s;
    __syncthreads();
    for (int off = 128; off > 0; off >>= 1) {
        if (tid < off) sh[tid] += sh[tid + off];
        __syncthreads();
    }
    if (tid == 0) part[plane * NCH + b] = sh[0];
}

__global__ void finalize_kernel(const double* __restrict__ part,
                                float* __restrict__ disp, float* __restrict__ fm) {
    __shared__ float feats[48];
    int tid = threadIdx.x;
    if (tid < 48) {
        double s = 0.0;
        for (int k = 0; k < NCH; ++k) s += part[tid * NCH + k];
        feats[tid] = (float)s;
    }
    __syncthreads();
    if (tid < NT) {
        float f0 = feats[tid * 3 + 0];
        float f1 = feats[tid * 3 + 1];
        float f2 = feats[tid * 3 + 2];
        disp[2 * tid + 0] = tanhf(f0) * 2.0f;
        disp[2 * tid + 1] = tanhf(f1) * 2.0f;
        fm[tid] = ((f0 + f1) + f2) / 3.0f;
    }
}

__global__ __launch_bounds__(256) void main_kernel(
        const float* __restrict__ video, const float* __restrict__ depth,
        const float* __restrict__ disp, const float* __restrict__ fm,
        float* __restrict__ out) {
    int tid = threadIdx.x;
    int t = blockIdx.x / 192;           /* 192 blocks per frame */
    int blk = blockIdx.x - t * 192;     /* block covers 1024 px = 2 rows */
    int lp0 = tid * 4;                  /* local pixel base (0..1020) */
    int y = blk * 2 + (tid >> 7);
    int x0 = (tid & 127) << 2;

    float dx = disp[2 * t + 0];
    float dy = disp[2 * t + 1];
    float fmt = fm[t];
    float tf = (float)t;

    /* y/t-invariant depth-row setup (valid for covered pixels) */
    float tyv = fminf(fmaxf((float)y + tf * dy, 0.f), 383.f);
    int y0 = (int)floorf(tyv);
    int y1 = min(y0 + 1, RES_H - 1);
    float wy = tyv - (float)y0;
    const float* dep = depth + (size_t)t * PLANE;
    int dro0 = (y0 + (y0 >> 2)) * SRC_W;
    int dro1 = (y1 + (y1 >> 2)) * SRC_W;
    float ytrk_c = tyv * SCALE_Y;

    const float* vt = video + (size_t)t * 3 * PLANE;

    float xt[4], yt[4], dv[4], vv[4], X4[4], Y4[4], col0[4], col1[4], col2[4];

#pragma unroll
    for (int k = 0; k < 4; ++k) {
        int x = x0 + k;
        bool covered = (x < 510);
        float xtrk = 0.f, ytrk = 0.f, dval = 0.f, visv = 0.f;
        if (covered) {
            float txv = fminf(fmaxf((float)x + tf * dx, 0.f), 511.f);
            int xi0 = (int)floorf(txv);
            int xi1 = min(xi0 + 1, RES_W - 1);
            float wx = txv - (float)xi0;
            int sx0 = xi0 + (xi0 >> 2);
            int sx1 = xi1 + (xi1 >> 2);
            float d00 = dep[dro0 + sx0];
            float d01 = dep[dro0 + sx1];
            float d10 = dep[dro1 + sx0];
            float d11 = dep[dro1 + sx1];
            dval = d00 * ((1.f - wx) * (1.f - wy)) + d01 * (wx * (1.f - wy))
                 + d10 * ((1.f - wx) * wy) + d11 * (wx * wy);
            float z = 3.0f * __sinf(0.05f * (float)(x + y)) + fmt;
            visv = (z > 1.38629436f) ? 1.f : 0.f;   /* sigmoid(z)>0.8 <=> z>ln4 */
            xtrk = txv * SCALE_X;
            ytrk = ytrk_c;
        }
        xt[k] = xtrk; yt[k] = ytrk; dv[k] = dval; vv[k] = visv;
        X4[k] = (xtrk - 320.f) / 640.f;
        Y4[k] = (ytrk - 240.f) / 640.f;

        /* grid-sample coords, stepwise like the reference */
        float a1 = xtrk / 640.f; float b1 = 2.f * (a1 - 0.5f); float c1 = b1 + 1.f;
        float px = (c1 * 0.5f) * 639.f;
        float a2 = ytrk / 480.f; float b2 = 2.f * (a2 - 0.5f); float c2 = b2 + 1.f;
        float py = (c2 * 0.5f) * 479.f;
        px = fminf(fmaxf(px, 0.f), 639.f);
        py = fminf(fmaxf(py, 0.f), 479.f);
        int cx0 = (int)floorf(px); int cx1 = min(cx0 + 1, SRC_W - 1); float cwx = px - (float)cx0;
        int cy0 = (int)floorf(py); int cy1 = min(cy0 + 1, SRC_H - 1); float cwy = py - (float)cy0;
        float w00 = (1.f - cwx) * (1.f - cwy), w01 = cwx * (1.f - cwy);
        float w10 = (1.f - cwx) * cwy,         w11 = cwx * cwy;
        int r0 = cy0 * SRC_W, r1 = cy1 * SRC_W;
        {
            const float* vc = vt;
            col0[k] = vc[r0 + cx0] * w00 + vc[r0 + cx1] * w01 + vc[r1 + cx0] * w10 + vc[r1 + cx1] * w11;
            vc += PLANE;
            col1[k] = vc[r0 + cx0] * w00 + vc[r0 + cx1] * w01 + vc[r1 + cx0] * w10 + vc[r1 + cx1] * w11;
            vc += PLANE;
            col2[k] = vc[r0 + cx0] * w00 + vc[r0 + cx1] * w01 + vc[r1 + cx0] * w10 + vc[r1 + cx1] * w11;
        }
    }

    size_t tb_blk = (size_t)t * NPIX + (size_t)blk * 1024;  /* block pixel base */
    size_t tb0 = tb_blk + (size_t)lp0;                       /* thread pixel base */

    /* direct nt stores: per-instruction wave-contiguous */
    __builtin_nontemporal_store((f32x4){dv[0], dv[1], dv[2], dv[3]},
                                (f32x4*)(out + O_Z + tb0));
    __builtin_nontemporal_store((f32x4){vv[0], vv[1], vv[2], vv[3]},
                                (f32x4*)(out + O_VIS + tb0));
    if ((y & 3) == 0) {
        int ns = (y >> 2) * 128 + (x0 >> 2);
        size_t sb = (size_t)t * (96 * 128) + (size_t)ns;
        __builtin_nontemporal_store((f32x2){xt[0], yt[0]},
                                    (f32x2*)(out + O_SPARSE + sb * 2));
    }

    /* LDS-staged transpose so traj/xy stores are lane-linear f32x4 */
    __shared__ float ls[7168];          /* 28 KB union buffer */
    f32x4* ls4 = (f32x4*)ls;

    /* phase A: traj — component-major staging */
    ls4[0 * 256 + tid] = (f32x4){X4[0], X4[1], X4[2], X4[3]};
    ls4[1 * 256 + tid] = (f32x4){Y4[0], Y4[1], Y4[2], Y4[3]};
    ls4[2 * 256 + tid] = (f32x4){dv[0], dv[1], dv[2], dv[3]};
    ls4[3 * 256 + tid] = (f32x4){col0[0], col0[1], col0[2], col0[3]};
    ls4[4 * 256 + tid] = (f32x4){col1[0], col1[1], col1[2], col1[3]};
    ls4[5 * 256 + tid] = (f32x4){col2[0], col2[1], col2[2], col2[3]};
    ls4[6 * 256 + tid] = (f32x4){vv[0], vv[1], vv[2], vv[3]};
    __syncthreads();
    {
        f32x4* tr4 = (f32x4*)(out + O_TRAJ + tb_blk * 7);
#pragma unroll
        for (int s = 0; s < 7; ++s) {
            unsigned m = (unsigned)(s * 256 + tid);
            unsigned e = 4u * m;
            unsigned p0 = (e + 0u) / 7u, c0 = (e + 0u) - p0 * 7u;
            unsigned p1 = (e + 1u) / 7u, c1 = (e + 1u) - p1 * 7u;
            unsigned p2 = (e + 2u) / 7u, c2 = (e + 2u) - p2 * 7u;
            unsigned p3 = (e + 3u) / 7u, c3 = (e + 3u) - p3 * 7u;
            f32x4 w = {ls[c0 * 1024 + p0], ls[c1 * 1024 + p1],
                       ls[c2 * 1024 + p2], ls[c3 * 1024 + p3]};
            __builtin_nontemporal_store(w, tr4 + m);
        }
    }
    __syncthreads();

    /* phase B: xy — pair-vector staging */
    ls4[tid]       = (f32x4){xt[0], yt[0], xt[1], yt[1]};
    ls4[256 + tid] = (f32x4){xt[2], yt[2], xt[3], yt[3]};
    __syncthreads();
    {
        f32x4* xy4 = (f32x4*)(out + O_XY + tb_blk * 2);
#pragma unroll
        for (int s = 0; s < 2; ++s) {
            unsigned m = (unsigned)(s * 256 + tid);
            unsigned idx = (m & 1u) * 256u + (m >> 1);
            __builtin_nontemporal_store(ls4[idx], xy4 + m);
        }
    }
}

extern "C" void kernel_launch(void* const* d_in, const int* in_sizes, int n_in,
                              void* d_out, int out_size, void* d_ws, size_t ws_size,
                              hipStream_t stream) {
    const float* video = (const float*)d_in[0];
    const float* depth = (const float*)d_in[1];
    float* out = (float*)d_out;

    double* part = (double*)d_ws;            /* 48*30 doubles = 11520 B */
    float* wsf = (float*)d_ws;
    float* disp = wsf + 2880;                /* 32 */
    float* fm = wsf + 2912;                  /* 16 */

    feat_kernel<<<dim3(NCH, NT * 3), 256, 0, stream>>>(video, part);
    finalize_kernel<<<1, 64, 0, stream>>>(part, disp, fm);
    main_kernel<<<NT * 192, 256, 0, stream>>>(video, depth, disp, fm, out);
}